// Round 2
// baseline (347.887 us; speedup 1.0000x reference)
//
#include <hip/hip_runtime.h>
#include <math.h>

// Workspace float offsets
#define OFF_AT  0         // At  [256 h][64 r]   : A[r][h] transposed, w(h) folded
#define OFF_BMT 16384     // BmT [256 w][32 y]   : w(w) folded
#define OFF_CMT 24576     // CmT [64 r][256 h]   : mode-weight folded
#define OFF_DMT 40960     // DmT [32 y][256 w]   : y-weight folded
#define OFF_T   49152     // T1 [512][256 h][32 y]  /  T2t [512][32 y][256 h] (shared)
#define OFF_Y   4243456   // Y [8][64][64 r][32 y]
#define OFF_Z   5292032   // Z [8][64][64 r][32 y]   (end: 6340608 floats = 25.4 MB)

__device__ __forceinline__ float cosT(int p) {
    // cos(pi * p / 255), exact integer argument reduction to [0, pi]
    int r = p % 510;
    if (r > 255) r = 510 - r;
    return cosf((float)r * (3.14159265358979323846f / 255.0f));
}

__global__ __launch_bounds__(256) void init_basis(float* __restrict__ ws) {
    int idx = blockIdx.x * 256 + threadIdx.x;
    if (idx < 16384) {                       // At[h][r]
        int h = idx >> 6, r = idx & 63;
        int k1 = (r < 32) ? r : r + 192;
        float we = (h == 0 || h == 255) ? 1.f : 2.f;
        ws[OFF_AT + idx] = we * cosT(k1 * h);
    } else if (idx < 24576) {                // BmT[w][y]
        int j = idx - 16384; int w = j >> 5, y = j & 31;
        float we = (w == 0 || w == 255) ? 1.f : 2.f;
        ws[OFF_BMT + j] = we * cosT(y * w);
    } else if (idx < 40960) {                // CmT[r][h]
        int j = idx - 24576; int r = j >> 8, h = j & 255;
        int k1 = (r < 32) ? r : r + 192;
        float wsl = (r == 0 || r == 63) ? 1.f : 2.f;
        ws[OFF_CMT + j] = wsl * cosT(k1 * h);
    } else if (idx < 49152) {                // DmT[y][w]
        int j = idx - 40960; int y = j >> 8, w = j & 255;
        float wy = (y == 0) ? 1.f : 2.f;
        ws[OFF_DMT + j] = wy * cosT(y * w);
    }
}

// ---------------- fwd1: T1[bi][h][y] = sum_w x[bi][h][w] * BmT[w][y] ----------------
// grid 1024: (bi, row-half of 128). Thread: rows {l, l+64}, 8 y.
__global__ __launch_bounds__(256) void fwd1_kernel(const float* __restrict__ x,
                                                   const float* __restrict__ ws,
                                                   float* __restrict__ T1) {
    __shared__ float xs[128 * 33];   // 16.9 KB, pad 33: read bank (l+w)%32 -> 2-way free
    __shared__ float bs[32 * 32];    // B chunk [32 w][32 y]
    const int t = threadIdx.x;
    const int bi = blockIdx.x >> 1;
    const int rt = (blockIdx.x & 1) * 128;
    const float* xp = x + (size_t)bi * 65536 + (size_t)rt * 256;
    const int l = t & 63;
    const int y8 = (t >> 6) * 8;
    const int colv = (t & 7) * 4;
    const int rbase = t >> 3;        // 0..31

    float acc0[8], acc1[8];
#pragma unroll
    for (int yy = 0; yy < 8; ++yy) { acc0[yy] = 0.f; acc1[yy] = 0.f; }

    for (int c = 0; c < 8; ++c) {
#pragma unroll
        for (int r = 0; r < 4; ++r) {
            int row = r * 32 + rbase;
            float4 v = *(const float4*)(xp + row * 256 + c * 32 + colv);
            float* dst = &xs[row * 33 + colv];
            dst[0] = v.x; dst[1] = v.y; dst[2] = v.z; dst[3] = v.w;
        }
        {
            int wloc = t >> 3;
            int y4 = (t & 7) * 4;
            *(float4*)&bs[wloc * 32 + y4] =
                *(const float4*)(ws + OFF_BMT + (c * 32 + wloc) * 32 + y4);
        }
        __syncthreads();
#pragma unroll 8
        for (int w = 0; w < 32; ++w) {
            float xv0 = xs[l * 33 + w];
            float xv1 = xs[(l + 64) * 33 + w];
            float4 b0 = *(float4*)&bs[w * 32 + y8];      // wave-uniform broadcast
            float4 b1 = *(float4*)&bs[w * 32 + y8 + 4];
            float bv[8] = {b0.x, b0.y, b0.z, b0.w, b1.x, b1.y, b1.z, b1.w};
#pragma unroll
            for (int yy = 0; yy < 8; ++yy) {
                acc0[yy] += xv0 * bv[yy];
                acc1[yy] += xv1 * bv[yy];
            }
        }
        __syncthreads();
    }
    float* Tp = T1 + (size_t)bi * 8192 + (size_t)(rt + l) * 32 + y8;
    *(float4*)Tp       = make_float4(acc0[0], acc0[1], acc0[2], acc0[3]);
    *(float4*)(Tp + 4) = make_float4(acc0[4], acc0[5], acc0[6], acc0[7]);
    Tp += 64 * 32;
    *(float4*)Tp       = make_float4(acc1[0], acc1[1], acc1[2], acc1[3]);
    *(float4*)(Tp + 4) = make_float4(acc1[4], acc1[5], acc1[6], acc1[7]);
}

// ---------------- fwd2: Y[bi][r][y] = sum_h At[h][r] * T1[bi][h][y] ----------------
__global__ __launch_bounds__(256) void fwd2_kernel(const float* __restrict__ ws,
                                                   const float* __restrict__ T1,
                                                   float* __restrict__ Y) {
    __shared__ float t1s[8192];      // [256 h][32 y]
    const int t = threadIdx.x;
    const int bi = blockIdx.x;
    const float* Tp = T1 + (size_t)bi * 8192;
#pragma unroll
    for (int k = 0; k < 8; ++k)
        *(float4*)&t1s[k * 1024 + t * 4] = *(const float4*)(Tp + k * 1024 + t * 4);
    __syncthreads();
    const int l = t & 63;            // r
    const int y8 = (t >> 6) * 8;
    float acc[8];
#pragma unroll
    for (int yy = 0; yy < 8; ++yy) acc[yy] = 0.f;
    const float* At = ws + OFF_AT + l;
#pragma unroll 4
    for (int h = 0; h < 256; ++h) {
        float av = At[h * 64];                       // lane-consecutive, L2-hot
        float4 t0 = *(float4*)&t1s[h * 32 + y8];     // broadcast
        float4 t1v = *(float4*)&t1s[h * 32 + y8 + 4];
        acc[0] += av * t0.x;  acc[1] += av * t0.y;
        acc[2] += av * t0.z;  acc[3] += av * t0.w;
        acc[4] += av * t1v.x; acc[5] += av * t1v.y;
        acc[6] += av * t1v.z; acc[7] += av * t1v.w;
    }
    float* Yp = Y + (size_t)bi * 2048 + l * 32 + y8;
    *(float4*)Yp       = make_float4(acc[0], acc[1], acc[2], acc[3]);
    *(float4*)(Yp + 4) = make_float4(acc[4], acc[5], acc[6], acc[7]);
}

// ---------------- mix: Z[b,o,r,y] = sum_i Y[b,i,r,y] * W[i,o,r,y] ----------------
__global__ __launch_bounds__(256) void mix_kernel(const float* __restrict__ w1,
                                                  const float* __restrict__ w2,
                                                  const float* __restrict__ Yv,
                                                  float* __restrict__ Z) {
    const int xp = blockIdx.x & 63;
    const int o0 = (blockIdx.x >> 6) * 16;
    const int t = threadIdx.x;
    const int yh = t & 15;
    const int oo = t >> 4;
    const int o = o0 + oo;
    const int y = yh * 2;

    const float* Wbase = (xp < 32) ? (w1 + xp * 32) : (w2 + (xp - 32) * 32);
    Wbase += o * 1024 + y;
    const float* Yb = Yv + xp * 32 + y;

    float acc[8][2];
#pragma unroll
    for (int b = 0; b < 8; ++b) { acc[b][0] = 0.f; acc[b][1] = 0.f; }

    for (int i = 0; i < 64; ++i) {
        float2 wv = *(const float2*)(Wbase + i * 65536);
#pragma unroll
        for (int b = 0; b < 8; ++b) {
            float2 yv = *(const float2*)(Yb + (b * 64 + i) * 2048);
            acc[b][0] += yv.x * wv.x;
            acc[b][1] += yv.y * wv.y;
        }
    }
#pragma unroll
    for (int b = 0; b < 8; ++b) {
        float2 r; r.x = acc[b][0]; r.y = acc[b][1];
        *(float2*)(Z + (size_t)(b * 64 + o) * 2048 + xp * 32 + y) = r;
    }
}

// ---------------- inv1: T2t[bo][y][h] = sum_r CmT[r][h] * Z[bo][r][y] ----------------
// grid 1024: (bo, h-half of 128). Output stored [y][h] so inv2 stages coalesced.
__global__ __launch_bounds__(256) void inv1_kernel(const float* __restrict__ ws,
                                                   const float* __restrict__ Zv,
                                                   float* __restrict__ T2) {
    __shared__ float zs[2048];       // [64 r][32 y]
    const int t = threadIdx.x;
    const int bo = blockIdx.x >> 1;
    const int ht = (blockIdx.x & 1) * 128;
    const float* Zp = Zv + (size_t)bo * 2048;
    *(float4*)&zs[t * 8]     = *(const float4*)(Zp + t * 8);
    *(float4*)&zs[t * 8 + 4] = *(const float4*)(Zp + t * 8 + 4);
    __syncthreads();
    const int l = t & 63;            // h within half-tile (and +64)
    const int y8 = (t >> 6) * 8;
    float acc0[8], acc1[8];
#pragma unroll
    for (int yy = 0; yy < 8; ++yy) { acc0[yy] = 0.f; acc1[yy] = 0.f; }
    const float* Cm = ws + OFF_CMT + ht + l;
#pragma unroll 4
    for (int r = 0; r < 64; ++r) {
        float a0 = Cm[r * 256];                      // coalesced, L2-hot
        float a1 = Cm[r * 256 + 64];
        float4 z0 = *(float4*)&zs[r * 32 + y8];      // broadcast
        float4 z1 = *(float4*)&zs[r * 32 + y8 + 4];
        float zv[8] = {z0.x, z0.y, z0.z, z0.w, z1.x, z1.y, z1.z, z1.w};
#pragma unroll
        for (int yy = 0; yy < 8; ++yy) {
            acc0[yy] += a0 * zv[yy];
            acc1[yy] += a1 * zv[yy];
        }
    }
    float* Tp = T2 + (size_t)bo * 8192 + (size_t)y8 * 256 + ht + l;
#pragma unroll
    for (int j = 0; j < 8; ++j) {
        Tp[j * 256]      = acc0[j];                  // lane-coalesced 256B rows
        Tp[j * 256 + 64] = acc1[j];
    }
}

// ---------------- inv2: out[bo][h][w] = sum_y T2t[bo][y][h] * DmT[y][w] ----------------
// grid 2048: (bo, h-quarter of 64). Thread: 8h x 8w register tile.
__global__ __launch_bounds__(256) void inv2_kernel(const float* __restrict__ ws,
                                                   const float* __restrict__ T2,
                                                   float* __restrict__ out) {
    __shared__ float t2s[32 * 68];   // [32 y][64 h + pad4]
    const int t = threadIdx.x;
    const int bo = blockIdx.x >> 2;
    const int ht = (blockIdx.x & 3) * 64;
    const float* Tp = T2 + (size_t)bo * 8192 + ht;
    {
        int y = t >> 3;
        int c8 = (t & 7) * 8;
        *(float4*)&t2s[y * 68 + c8]     = *(const float4*)(Tp + y * 256 + c8);
        *(float4*)&t2s[y * 68 + c8 + 4] = *(const float4*)(Tp + y * 256 + c8 + 4);
    }
    __syncthreads();
    const int h8 = (t >> 5) * 8;     // 8 groups -> 64 h
    const int w8 = (t & 31) * 8;     // 32 groups -> 256 w
    const float* Dm = ws + OFF_DMT + w8;   // 32 KB table: L1/L2 resident
    float a2[8][8];
#pragma unroll
    for (int i = 0; i < 8; ++i)
#pragma unroll
        for (int w = 0; w < 8; ++w) a2[i][w] = 0.f;
#pragma unroll 4
    for (int y = 0; y < 32; ++y) {
        float4 ta = *(float4*)&t2s[y * 68 + h8];         // 2-addr broadcast
        float4 tb = *(float4*)&t2s[y * 68 + h8 + 4];
        float4 da = *(const float4*)(Dm + y * 256);
        float4 db = *(const float4*)(Dm + y * 256 + 4);
        float tv[8] = {ta.x, ta.y, ta.z, ta.w, tb.x, tb.y, tb.z, tb.w};
        float dv[8] = {da.x, da.y, da.z, da.w, db.x, db.y, db.z, db.w};
#pragma unroll
        for (int i = 0; i < 8; ++i)
#pragma unroll
            for (int w = 0; w < 8; ++w)
                a2[i][w] += tv[i] * dv[w];
    }
    float* op = out + (size_t)bo * 65536 + (size_t)(ht + h8) * 256 + w8;
#pragma unroll
    for (int i = 0; i < 8; ++i) {
        *(float4*)(op + i * 256)     = make_float4(a2[i][0], a2[i][1], a2[i][2], a2[i][3]);
        *(float4*)(op + i * 256 + 4) = make_float4(a2[i][4], a2[i][5], a2[i][6], a2[i][7]);
    }
}

extern "C" void kernel_launch(void* const* d_in, const int* in_sizes, int n_in,
                              void* d_out, int out_size, void* d_ws, size_t ws_size,
                              hipStream_t stream) {
    const float* x  = (const float*)d_in[0];
    const float* w1 = (const float*)d_in[1];
    const float* w2 = (const float*)d_in[2];
    float* out = (float*)d_out;
    float* ws  = (float*)d_ws;   // needs ~25.4 MB

    hipLaunchKernelGGL(init_basis, dim3(192), dim3(256), 0, stream, ws);
    hipLaunchKernelGGL(fwd1_kernel, dim3(1024), dim3(256), 0, stream, x, ws, ws + OFF_T);
    hipLaunchKernelGGL(fwd2_kernel, dim3(512), dim3(256), 0, stream, ws, ws + OFF_T, ws + OFF_Y);
    hipLaunchKernelGGL(mix_kernel, dim3(256), dim3(256), 0, stream, w1, w2,
                       ws + OFF_Y, ws + OFF_Z);
    hipLaunchKernelGGL(inv1_kernel, dim3(1024), dim3(256), 0, stream, ws, ws + OFF_Z, ws + OFF_T);
    hipLaunchKernelGGL(inv2_kernel, dim3(2048), dim3(256), 0, stream, ws, ws + OFF_T, out);
}